// Round 2
// baseline (231.482 us; speedup 1.0000x reference)
//
#include <hip/hip_runtime.h>

// x: [B=32, C=1, F=257, T=4096] float32 log-magnitude spectrogram
// SHIFT_BINS = 0.64 -> f_low = f, f_high = f+1
//   out[b,f,t] = log10((1-a)*10^x[b,f,t] + a*10^x[b,f+1,t] + 1e-8), f < 256
//   out[b,256,t] = log10(1e-8)  (valid mask false at top bin)
//
// R1 structure: f-strip blocking. Each block computes R=8 output rows from
// R+1=9 input rows (reuse along f lives in registers), cutting HBM reads
// from 2x to 1.125x of the input. 287 MB total traffic -> ~45 us floor.
#define B_DIM 32
#define F_DIM 257
#define T_DIM 4096
#define TV    (T_DIM / 4)   // row length in float4 = 1024
#define R     8             // output rows per block
#define EPS_F 1e-8f

#define LOG2_10  3.32192809488736234787f
#define LOG10_2  0.30102999566398119521f

__device__ __forceinline__ float pow10_fast(float v) {
    return __builtin_amdgcn_exp2f(v * LOG2_10);   // v_exp_f32, ~1 ulp
}
__device__ __forceinline__ float log10_fast(float v) {
    return __builtin_amdgcn_logf(v) * LOG10_2;    // v_log_f32 is log2
}

// grid: (colgroups=4, strips=33, B=32), block=256
// strip s<32: output rows f = 8s..8s+7, reads input rows 8s..8s+8
// strip s==32: constant top row (f=256)
__global__ __launch_bounds__(256) void freq_shift_strip(
        const float* __restrict__ x, float* __restrict__ out) {
    const int cg  = blockIdx.x;           // column group 0..3
    const int s   = blockIdx.y;           // strip 0..32
    const int b   = blockIdx.z;           // batch 0..31
    const int col = cg * 256 + threadIdx.x;   // float4 column 0..1023

    const long long bbase = (long long)b * F_DIM * T_DIM;
    float4* __restrict__ orow = (float4*)(out + bbase);

    if (s == 32) {
        // top bin: log10(0 + 1e-8); whole block uniform
        const float cv = log10_fast(EPS_F);
        orow[(F_DIM - 1) * TV + col] = make_float4(cv, cv, cv, cv);
        return;
    }

    const int f0 = s * R;
    const float4* __restrict__ xrow = (const float4*)(x + bbase);

    // Load 9 rows' worth of this thread's column chunk, exponentiate once.
    // (10^x values are shared by the two adjacent output rows.)
    float4 e[R + 1];
#pragma unroll
    for (int k = 0; k <= R; ++k) {
        const float4 a = xrow[(f0 + k) * TV + col];
        e[k].x = pow10_fast(a.x);
        e[k].y = pow10_fast(a.y);
        e[k].z = pow10_fast(a.z);
        e[k].w = pow10_fast(a.w);
    }

#pragma unroll
    for (int r = 0; r < R; ++r) {
        // reference fp32 alpha: fl(f + 0.64f) - f  (exact by Sterbenz)
        const float ff    = (float)(f0 + r);
        const float alpha = (ff + 0.64f) - ff;
        const float beta  = 1.0f - alpha;
        float4 o;
        o.x = log10_fast(beta * e[r].x + alpha * e[r + 1].x + EPS_F);
        o.y = log10_fast(beta * e[r].y + alpha * e[r + 1].y + EPS_F);
        o.z = log10_fast(beta * e[r].z + alpha * e[r + 1].z + EPS_F);
        o.w = log10_fast(beta * e[r].w + alpha * e[r + 1].w + EPS_F);
        orow[(f0 + r) * TV + col] = o;
    }
}

extern "C" void kernel_launch(void* const* d_in, const int* in_sizes, int n_in,
                              void* d_out, int out_size, void* d_ws, size_t ws_size,
                              hipStream_t stream) {
    const float* x = (const float*)d_in[0];
    float* out = (float*)d_out;
    dim3 grid(T_DIM / 4 / 256, F_DIM / R + 1, B_DIM);  // (4, 33, 32)
    dim3 block(256);
    freq_shift_strip<<<grid, block, 0, stream>>>(x, out);
}

// Round 4
// 230.157 us; speedup vs baseline: 1.0058x; 1.0058x over previous
//
#include <hip/hip_runtime.h>

// x: [B=32, C=1, F=257, T=4096] float32 log-magnitude spectrogram
// SHIFT_BINS = 0.64 -> f_low = f, f_high = f+1
//   out[b,f,t] = log10((1-a)*10^x[b,f,t] + a*10^x[b,f+1,t] + 1e-8), f < 256
//   out[b,256,t] = log10(1e-8)  (valid mask false at top bin)
//
// R3 = R2 with the compile fix: __builtin_nontemporal_store needs a clang
// native vector, not HIP's float4 class -> use ext_vector_type(4) throughout.
// Structure: f-strip blocking (R=8 outputs from 9 input rows, reuse in regs),
// all 9 row-loads issued before any exp2 (MLP), __launch_bounds__(256,4) for
// VGPR headroom, non-temporal stores so the 135 MB output doesn't evict
// input rows from L2/L3.
#define B_DIM 32
#define F_DIM 257
#define T_DIM 4096
#define TV    (T_DIM / 4)   // row length in float4 = 1024
#define R     8             // output rows per block
#define EPS_F 1e-8f

#define LOG2_10  3.32192809488736234787f
#define LOG10_2  0.30102999566398119521f

typedef float v4f __attribute__((ext_vector_type(4)));

__device__ __forceinline__ float pow10_fast(float v) {
    return __builtin_amdgcn_exp2f(v * LOG2_10);   // v_exp_f32, ~1 ulp
}
__device__ __forceinline__ float log10_fast(float v) {
    return __builtin_amdgcn_logf(v) * LOG10_2;    // v_log_f32 is log2
}

__device__ __forceinline__ v4f exp4(v4f a) {
    v4f r;
    r.x = pow10_fast(a.x); r.y = pow10_fast(a.y);
    r.z = pow10_fast(a.z); r.w = pow10_fast(a.w);
    return r;
}

// grid: (colgroups=4, strips=33, B=32), block=256
__global__ __launch_bounds__(256, 4) void freq_shift_strip(
        const float* __restrict__ x, float* __restrict__ out) {
    const int cg  = blockIdx.x;               // column group 0..3
    const int s   = blockIdx.y;               // strip 0..32
    const int b   = blockIdx.z;               // batch 0..31
    const int col = cg * 256 + threadIdx.x;   // float4 column 0..1023

    const long long bbase = (long long)b * F_DIM * T_DIM;
    v4f* __restrict__ orow = (v4f*)(out + bbase);

    if (s == 32) {
        const float cv = log10_fast(EPS_F);   // top bin: log10(0 + 1e-8)
        v4f v; v.x = cv; v.y = cv; v.z = cv; v.w = cv;
        __builtin_nontemporal_store(v, &orow[(F_DIM - 1) * TV + col]);
        return;
    }

    const int f0 = s * R;
    const v4f* __restrict__ xrow = (const v4f*)(x + bbase + (long long)f0 * T_DIM);

    // ---- phase 1: issue ALL 9 loads (independent, 36 VGPRs of data) ----
    v4f a0 = xrow[0 * TV + col];
    v4f a1 = xrow[1 * TV + col];
    v4f a2 = xrow[2 * TV + col];
    v4f a3 = xrow[3 * TV + col];
    v4f a4 = xrow[4 * TV + col];
    v4f a5 = xrow[5 * TV + col];
    v4f a6 = xrow[6 * TV + col];
    v4f a7 = xrow[7 * TV + col];
    v4f a8 = xrow[8 * TV + col];

    // ---- phase 2: exponentiate in place ----
    a0 = exp4(a0); a1 = exp4(a1); a2 = exp4(a2); a3 = exp4(a3); a4 = exp4(a4);
    a5 = exp4(a5); a6 = exp4(a6); a7 = exp4(a7); a8 = exp4(a8);

    // ---- phase 3: interpolate + log10, non-temporal stores ----
    v4f e[R + 1] = {a0, a1, a2, a3, a4, a5, a6, a7, a8};
#pragma unroll
    for (int r = 0; r < R; ++r) {
        // reference fp32 alpha: fl(f + 0.64f) - f  (exact by Sterbenz)
        const float ff    = (float)(f0 + r);
        const float alpha = (ff + 0.64f) - ff;
        const float beta  = 1.0f - alpha;
        v4f o;
        o.x = log10_fast(beta * e[r].x + alpha * e[r + 1].x + EPS_F);
        o.y = log10_fast(beta * e[r].y + alpha * e[r + 1].y + EPS_F);
        o.z = log10_fast(beta * e[r].z + alpha * e[r + 1].z + EPS_F);
        o.w = log10_fast(beta * e[r].w + alpha * e[r + 1].w + EPS_F);
        __builtin_nontemporal_store(o, &orow[(f0 + r) * TV + col]);
    }
}

extern "C" void kernel_launch(void* const* d_in, const int* in_sizes, int n_in,
                              void* d_out, int out_size, void* d_ws, size_t ws_size,
                              hipStream_t stream) {
    const float* x = (const float*)d_in[0];
    float* out = (float*)d_out;
    dim3 grid(T_DIM / 4 / 256, F_DIM / R + 1, B_DIM);  // (4, 33, 32)
    dim3 block(256);
    freq_shift_strip<<<grid, block, 0, stream>>>(x, out);
}